// Round 15
// baseline (437.053 us; speedup 1.0000x reference)
//
#include <hip/hip_runtime.h>
#include <hip/hip_bf16.h>
#include <cstdio>
#include <cstdint>

typedef __bf16 bf16x8 __attribute__((ext_vector_type(8)));
typedef unsigned short u16;
typedef u16 u16x8 __attribute__((ext_vector_type(8)));
typedef float f32x4 __attribute__((ext_vector_type(4)));

#define DEV __device__ __forceinline__

static constexpr int B_ = 8, S_ = 2048, E_ = 768, NQ_ = 128, FF_ = 3072;
static constexpr int BS_ = B_ * S_;

DEV u16 f2b(float f) {
    unsigned u = __builtin_bit_cast(unsigned, f);
    unsigned r = (u + 0x7fffu + ((u >> 16) & 1u)) >> 16;
    return (u16)r;
}

#define GLD16(gp, lp) __builtin_amdgcn_global_load_lds( \
    (const __attribute__((address_space(1))) void*)(gp), \
    (__attribute__((address_space(3))) void*)(lp), 16, 0, 0)

// ---------------------------------------------------------------------------
// f32 -> bf16 convert (vectorized float4 -> ushort4)
// ---------------------------------------------------------------------------
__global__ void cvt_bf16(const float* __restrict__ in, u16* __restrict__ out, int n)
{
    const int stride = gridDim.x * blockDim.x * 4;
    for (int i = (blockIdx.x * blockDim.x + threadIdx.x) * 4; i < n; i += stride) {
        const float4 f = *(const float4*)(in + i);
        ushort4 u;
        u.x = f2b(f.x); u.y = f2b(f.y); u.z = f2b(f.z); u.w = f2b(f.w);
        *(ushort4*)(out + i) = u;
    }
}

// ---------------------------------------------------------------------------
// 128x128 GEMM, BK=64, 4 waves (2x2 of 64x64), 256 threads,
// DOUBLE-BUFFERED LDS (64 KiB), ONE __syncthreads per K-step.
//
// History driving this shape:
//  - asm-AGPR accumulator (rounds 2-8): compiler refuses to promote the acc
//    array -> scratch spill (0.9-1.25 GB writes/dispatch).  "a" constraints
//    + (1) first MFMA src-C = inline 0, (2) s_nop fence before epilogue.
//  - 128^2 tile (round 13): 256^2 under-fills the chip (192-block grids) at
//    1 block/CU; 128^2 = full chip + multi-block overlap.
//  - NO XCD swizzle (round 14): L3 already absorbs panel re-reads (FETCH =
//    compulsory); chunked swizzle put 8 batches in flight -> L3 thrash
//    (FETCH 93->301 MB).  Default block order is the good order.
//  - dbuf single-barrier loop (round 10: 141->94 us at 256^2): stage k+1
//    before compute k; one barrier drains vmcnt AND closes LDS reads.
//  - BK=64 row-swizzle ((row&7)<<4 byte-XOR): 0 bank conflicts (r10/12/13).
//  - counted-vmcnt/BK=32 (round 11): regressed, do not revisit.
// ---------------------------------------------------------------------------
template<int K>
DEV void kstage(const u16* A, const u16* Bm, u16* As, u16* Bs,
                int m0, int n0, int k0, int w, int t)
{
    #pragma unroll
    for (int r = 0; r < 4; ++r) {
        const int ci = r * 256 + t;
        const int row = ci >> 3;                       // 0..127
        const int colb = ((ci & 7) * 16) ^ ((row & 7) << 4);
        GLD16(A  + (size_t)(m0 + row) * K + k0 + (colb >> 1),
              As + (size_t)(r * 256 + w * 64) * 8);
        GLD16(Bm + (size_t)(n0 + row) * K + k0 + (colb >> 1),
              Bs + (size_t)(r * 256 + w * 64) * 8);
    }
}

template<bool FIRST>
DEV void kcompute(const u16* As, const u16* Bs, f32x4 (&acc)[4][4],
                  int wr, int wc, int lane)
{
    #pragma unroll
    for (int kk = 0; kk < 2; ++kk) {
        bf16x8 af[4], bf[4];
        const int cb = kk * 64 + ((lane >> 4) << 4);   // byte offset in row
        #pragma unroll
        for (int m = 0; m < 4; ++m) {
            const int row = wr * 64 + m * 16 + (lane & 15);
            af[m] = *(const bf16x8*)((const char*)As + row * 128 + (cb ^ ((row & 7) << 4)));
        }
        #pragma unroll
        for (int n = 0; n < 4; ++n) {
            const int row = wc * 64 + n * 16 + (lane & 15);
            bf[n] = *(const bf16x8*)((const char*)Bs + row * 128 + (cb ^ ((row & 7) << 4)));
        }
        #pragma unroll
        for (int m = 0; m < 4; ++m)
            #pragma unroll
            for (int n = 0; n < 4; ++n) {
                if (FIRST && kk == 0)
                    asm("v_mfma_f32_16x16x32_bf16 %0, %1, %2, 0"
                        : "=a"(acc[m][n]) : "v"(af[m]), "v"(bf[n]));
                else
                    asm("v_mfma_f32_16x16x32_bf16 %0, %1, %2, %0"
                        : "+a"(acc[m][n]) : "v"(af[m]), "v"(bf[n]));
            }
    }
}

// MODE 0: out bf16 = cos(c + bias[col]); aux = qaT       (qa)  [__cosf:
//         libm cosf spilled the live-acc epilogue, round 8]
// MODE 1: out bf16 = relu(c + bias[col])                 (h)
// MODE 2: out f32  = c + bias[col]                       (ffn)
// MODE 3: out f32  = c                                   (attn @ qa)
// MODE 4: out f32  = c * (1/sqrt(8))                     (scores; f32 logits)
template<int K, int MODE>
__global__ __launch_bounds__(256, 2)
void gemm_bt(const u16* __restrict__ A, const u16* __restrict__ Bm,
             const float* __restrict__ bias, void* __restrict__ out, int N,
             size_t sA, size_t sB, size_t sC, u16* __restrict__ aux)
{
    __shared__ u16 lds[4 * 128 * 64];      // 64 KiB: [A0|B0|A1|B1] x 16 KiB
    const int t = threadIdx.x;
    const int w = t >> 6, lane = t & 63;
    const int m0 = blockIdx.x * 128, n0 = blockIdx.y * 128;
    const int wr = w >> 1, wc = w & 1;     // 2 x 2 waves; wave tile 64x64
    A  += (size_t)blockIdx.z * sA;
    Bm += (size_t)blockIdx.z * sB;
    u16*   ob16 = (u16*)out   + (size_t)blockIdx.z * sC;
    float* of32 = (float*)out + (size_t)blockIdx.z * sC;
    f32x4 acc[4][4];               // written first by the C=0 MFMA form

    // prologue: stage tile 0; then pipeline {stage k+1 || compute k}
    kstage<K>(A, Bm, lds, lds + 8192, m0, n0, 0, w, t);
    __syncthreads();                       // drains vmcnt: buf0 ready
    int cur = 0;
    for (int k0 = 0; k0 < K; k0 += 64) {
        const int nxt = cur ^ 16384;
        if (k0 + 64 < K)
            kstage<K>(A, Bm, lds + nxt, lds + nxt + 8192, m0, n0, k0 + 64, w, t);
        if (k0 == 0) kcompute<true >(lds + cur, lds + cur + 8192, acc, wr, wc, lane);
        else         kcompute<false>(lds + cur, lds + cur + 8192, acc, wr, wc, lane);
        __syncthreads();                   // drains vmcnt: nxt ready; all
        cur = nxt;                         // waves done reading cur
    }

    // hazard fence: MFMA(write acc) -> VALU/accvgpr_read in epilogue
    __builtin_amdgcn_sched_barrier(0);
    asm volatile("s_nop 7\n\ts_nop 7");
    __builtin_amdgcn_sched_barrier(0);

    // epilogue: C/D layout col = lane&15, row = (lane>>4)*4 + r
    #pragma unroll
    for (int m = 0; m < 4; ++m) {
        const int rowb = m0 + wr * 64 + m * 16 + ((lane >> 4) << 2);
        #pragma unroll
        for (int n = 0; n < 4; ++n) {
            const int col = n0 + wc * 64 + n * 16 + (lane & 15);
            float bv = 0.f;
            if (MODE == 0 || MODE == 1 || MODE == 2) bv = bias[col];
            ushort4 tq;
            #pragma unroll
            for (int r = 0; r < 4; ++r) {
                const float c = acc[m][n][r];
                const size_t idx = (size_t)(rowb + r) * N + col;
                if (MODE == 0) {
                    const u16 v = f2b(__cosf(c + bv));
                    ob16[idx] = v;
                    ((u16*)&tq)[r] = v;
                }
                else if (MODE == 1) ob16[idx] = f2b(fmaxf(c + bv, 0.f));
                else if (MODE == 2) of32[idx] = c + bv;
                else if (MODE == 3) of32[idx] = c;
                else                of32[idx] = c * 0.35355339059327373f;
            }
            if (MODE == 0) {
                // qaT[b][col][srow..srow+3] (4-row quad is 128-tile-internal,
                // batches 2048-aligned -> never straddles a batch)
                const int b = rowb >> 11, srow = rowb & 2047;
                *(ushort4*)(aux + ((size_t)b * E_ + col) * S_ + srow) = tq;
            }
        }
    }
}

// ---------------------------------------------------------------------------
// Row softmax: read 2048 f32 logits, write 2048 bf16 probabilities.
// One block per row, 256 threads x 8 elements.
// ---------------------------------------------------------------------------
__global__ __launch_bounds__(256)
void softmax_rows(const float* __restrict__ s, u16* __restrict__ pout)
{
    const int t = threadIdx.x;
    const float* row = s + (size_t)blockIdx.x * (size_t)S_;
    float f[8];
    {
        const float4 a = *(const float4*)(row + t * 8);
        const float4 b = *(const float4*)(row + t * 8 + 4);
        f[0] = a.x; f[1] = a.y; f[2] = a.z; f[3] = a.w;
        f[4] = b.x; f[5] = b.y; f[6] = b.z; f[7] = b.w;
    }
    float mx = f[0];
    #pragma unroll
    for (int e = 1; e < 8; ++e) mx = fmaxf(mx, f[e]);
    #pragma unroll
    for (int d = 1; d < 64; d <<= 1) mx = fmaxf(mx, __shfl_xor(mx, d));
    __shared__ float sh[8];
    if ((t & 63) == 0) sh[t >> 6] = mx;
    __syncthreads();
    mx = fmaxf(fmaxf(sh[0], sh[1]), fmaxf(sh[2], sh[3]));
    float sum = 0.f;
    #pragma unroll
    for (int e = 0; e < 8; ++e) { f[e] = __expf(f[e] - mx); sum += f[e]; }
    #pragma unroll
    for (int d = 1; d < 64; d <<= 1) sum += __shfl_xor(sum, d);
    if ((t & 63) == 0) sh[4 + (t >> 6)] = sum;
    __syncthreads();
    sum = sh[4] + sh[5] + sh[6] + sh[7];
    const float inv = 1.f / sum;
    u16x8 v;
    #pragma unroll
    for (int e = 0; e < 8; ++e) v[e] = f2b(f[e] * inv);
    *(u16x8*)(pout + (size_t)blockIdx.x * (size_t)S_ + t * 8) = v;
}

// ---------------------------------------------------------------------------
// Fused residual + LayerNorm (+ optional qf = cos(y[:128] + theta) epilogue).
// One block per row (768 cols, 256 threads x 3).
// ---------------------------------------------------------------------------
__global__ __launch_bounds__(256)
void ln_fuse(const float* __restrict__ a, const float* __restrict__ res,
             const float* __restrict__ g, const float* __restrict__ bb,
             const float* __restrict__ theta, float* __restrict__ out,
             u16* __restrict__ qf)
{
    const int row = blockIdx.x, t = threadIdx.x;
    const float* ar = a + (size_t)row * E_;
    const float* rr = res + (size_t)row * E_;
    float v0 = ar[t] + rr[t];
    float v1 = ar[t + 256] + rr[t + 256];
    float v2 = ar[t + 512] + rr[t + 512];
    float s1 = v0 + v1 + v2;
    float s2 = v0 * v0 + v1 * v1 + v2 * v2;
    #pragma unroll
    for (int d = 1; d < 64; d <<= 1) { s1 += __shfl_xor(s1, d); s2 += __shfl_xor(s2, d); }
    __shared__ float sh[8];
    if ((t & 63) == 0) { sh[t >> 6] = s1; sh[4 + (t >> 6)] = s2; }
    __syncthreads();
    s1 = sh[0] + sh[1] + sh[2] + sh[3];
    s2 = sh[4] + sh[5] + sh[6] + sh[7];
    const float mean = s1 * (1.f / 768.f);
    const float var = s2 * (1.f / 768.f) - mean * mean;
    const float rs = rsqrtf(var + 1e-5f);
    float* orow = out + (size_t)row * E_;
    const float y0 = (v0 - mean) * rs * g[t] + bb[t];
    const float y1 = (v1 - mean) * rs * g[t + 256] + bb[t + 256];
    const float y2 = (v2 - mean) * rs * g[t + 512] + bb[t + 512];
    orow[t] = y0; orow[t + 256] = y1; orow[t + 512] = y2;
    if (qf != nullptr && t < NQ_)
        qf[(size_t)row * NQ_ + t] = f2b(cosf(y0 + theta[t]));
}

// ---------------------------------------------------------------------------
// Workspace arena plan (216 MiB arena + 5.25 MiB fixed tail).
// Timeline:  t0 cvt | t1 gemm0 (writes qa + qaT) | t3 scores | t4 softmax
//            t5 PV  | t6 ln1   | t7 ffn1         | t8 ffn2   | t9 ln2
// buffer   offset(MiB) size  live
//  x_b        0       24    t0-t1
//  Wp_b      24       1.13  t0-t1
//  qa       128       24    t1-t3
//  qaT      192       24    t1-t5
//  scores     0      128    t3-t4
//  probs    128       64    t4-t5
//  ao         0       48    t5-t6,t8-t9
//  x1       144       48    t6-t9
//  qf       192        4    t6-t7
//  h         48       96    t7-t8
// ---------------------------------------------------------------------------
extern "C" void kernel_launch(void* const* d_in, const int* in_sizes, int n_in,
                              void* d_out, int out_size, void* d_ws, size_t ws_size,
                              hipStream_t stream)
{
    (void)in_sizes; (void)n_in; (void)out_size;
    const float* x    = (const float*)d_in[0];
    const float* Wp   = (const float*)d_in[1];
    const float* trx  = (const float*)d_in[2];
    const float* try_ = (const float*)d_in[3];
    const float* W1   = (const float*)d_in[4];
    const float* b1   = (const float*)d_in[5];
    const float* W2   = (const float*)d_in[6];
    const float* b2   = (const float*)d_in[7];
    const float* g1   = (const float*)d_in[8];
    const float* bb1  = (const float*)d_in[9];
    const float* g2   = (const float*)d_in[10];
    const float* bb2  = (const float*)d_in[11];
    float* out = (float*)d_out;

    const size_t MiB = (size_t)1 << 20;
    char* arena = (char*)d_ws;
    u16*   x_b    = (u16*)  (arena + 0);
    u16*   Wp_b   = (u16*)  (arena + 24 * MiB);
    u16*   qa     = (u16*)  (arena + 128 * MiB);
    u16*   qaT    = (u16*)  (arena + 192 * MiB);
    float* scores = (float*)(arena + 0);
    u16*   probs  = (u16*)  (arena + 128 * MiB);
    float* ao     = (float*)(arena + 0);
    float* x1     = (float*)(arena + 144 * MiB);
    u16*   qf     = (u16*)  (arena + 192 * MiB);
    u16*   h      = (u16*)  (arena + 48 * MiB);
    u16*   W1_b   = (u16*)  (arena + 216 * MiB);
    u16*   W2_b   = (u16*)  (arena + 216 * MiB + (size_t)FF_ * NQ_ * 2);
    const size_t need = 216 * MiB + (size_t)FF_ * NQ_ * 2 + (size_t)E_ * FF_ * 2;
    if (need > ws_size) {
        fprintf(stderr, "kernel_launch: ws too small: need=%zu have=%zu\n", need, ws_size);
        return;
    }

    cvt_bf16<<<512, 256, 0, stream>>>(x,  x_b,  BS_ * E_);
    cvt_bf16<<<64,  256, 0, stream>>>(Wp, Wp_b, E_ * E_);
    cvt_bf16<<<64,  256, 0, stream>>>(W1, W1_b, FF_ * NQ_);
    cvt_bf16<<<64,  256, 0, stream>>>(W2, W2_b, E_ * FF_);

    // qa = cos(x @ Wp^T + theta_rx); epilogue also writes qaT[b][d][s]
    gemm_bt<E_, 0><<<dim3(BS_ / 128, E_ / 128), 256, 0, stream>>>(
        x_b, Wp_b, trx, qa, E_, 0, 0, 0, qaT);
    // scores = (qa @ qa^T) / sqrt(8), f32, per batch
    gemm_bt<E_, 4><<<dim3(S_ / 128, S_ / 128, B_), 256, 0, stream>>>(
        qa, qa, nullptr, scores, S_,
        (size_t)S_ * E_, (size_t)S_ * E_, (size_t)S_ * S_, nullptr);
    // probs = softmax(scores) in bf16
    softmax_rows<<<BS_, 256, 0, stream>>>(scores, probs);
    // ao = probs @ qa  (= probs [S,S] * qaT [E,S]^T), f32, per batch
    gemm_bt<S_, 3><<<dim3(S_ / 128, E_ / 128, B_), 256, 0, stream>>>(
        probs, qaT, nullptr, ao, E_,
        (size_t)S_ * S_, (size_t)E_ * S_, (size_t)S_ * E_, nullptr);

    ln_fuse<<<BS_, 256, 0, stream>>>(ao, x, g1, bb1, try_, x1, qf);
    gemm_bt<NQ_, 1><<<dim3(BS_ / 128, FF_ / 128), 256, 0, stream>>>(
        qf, W1_b, b1, h, FF_, 0, 0, 0, nullptr);
    gemm_bt<FF_, 2><<<dim3(BS_ / 128, E_ / 128), 256, 0, stream>>>(
        h, W2_b, b2, ao, E_, 0, 0, 0, nullptr);
    ln_fuse<<<BS_, 256, 0, stream>>>(ao, x1, g2, bb2, nullptr, out, nullptr);
}

// Round 16
// 409.933 us; speedup vs baseline: 1.0662x; 1.0662x over previous
//
#include <hip/hip_runtime.h>
#include <hip/hip_bf16.h>
#include <cstdio>
#include <cstdint>

typedef __bf16 bf16x8 __attribute__((ext_vector_type(8)));
typedef unsigned short u16;
typedef u16 u16x8 __attribute__((ext_vector_type(8)));
typedef float f32x4 __attribute__((ext_vector_type(4)));

#define DEV __device__ __forceinline__

static constexpr int B_ = 8, S_ = 2048, E_ = 768, NQ_ = 128, FF_ = 3072;
static constexpr int BS_ = B_ * S_;

DEV u16 f2b(float f) {
    unsigned u = __builtin_bit_cast(unsigned, f);
    unsigned r = (u + 0x7fffu + ((u >> 16) & 1u)) >> 16;
    return (u16)r;
}

#define GLD16(gp, lp) __builtin_amdgcn_global_load_lds( \
    (const __attribute__((address_space(1))) void*)(gp), \
    (__attribute__((address_space(3))) void*)(lp), 16, 0, 0)

// ---------------------------------------------------------------------------
// f32 -> bf16 convert (vectorized float4 -> ushort4)
// ---------------------------------------------------------------------------
__global__ void cvt_bf16(const float* __restrict__ in, u16* __restrict__ out, int n)
{
    const int stride = gridDim.x * blockDim.x * 4;
    for (int i = (blockIdx.x * blockDim.x + threadIdx.x) * 4; i < n; i += stride) {
        const float4 f = *(const float4*)(in + i);
        ushort4 u;
        u.x = f2b(f.x); u.y = f2b(f.y); u.z = f2b(f.z); u.w = f2b(f.w);
        *(ushort4*)(out + i) = u;
    }
}

// ---------------------------------------------------------------------------
// 128x128 GEMM (champion r13 structure): BK=64, 4 waves (2x2 of 64x64),
// 256 threads, SINGLE-buffer LDS (32 KiB) + 2 barriers/K-step, 3 blocks/CU.
// Session evidence locking this shape:
//  - asm-AGPR accumulator (r2-8): compiler never promotes acc -> scratch
//    spill; "a" constraints + C=0 first MFMA + s_nop fence fixed it.
//  - 128^2 single-buf @3 blocks/CU (r13, 406us) beats 256^2 dbuf (r12,
//    411), 128^2 dbuf @2 blocks/CU (r15, 437), counted-vmcnt (r11, 438),
//    XCD swizzle (r14, 414: L3 thrash, FETCH 93->301 MB).
//  - BK=64 row-swizzle ((row&7)<<4 byte-XOR): 0 bank conflicts.
//  - ffn2 at 814 TF = the documented m97-structure ceiling; further gains
//    need the m201 8-phase schedule (not reconstructible here).
// r16 change: MODE 0 epilogue writes qa ONLY -- the fused qaT scatter
// (16 ushort4/thread at 4 KB lane stride) made gemm0 4x less efficient
// than ffn2 (205 vs 814 TF); transpose restored as a separate kernel.
// ---------------------------------------------------------------------------
template<int K>
DEV void kstage(const u16* A, const u16* Bm, u16* As, u16* Bs,
                int m0, int n0, int k0, int w, int t)
{
    #pragma unroll
    for (int r = 0; r < 4; ++r) {
        const int ci = r * 256 + t;
        const int row = ci >> 3;                       // 0..127
        const int colb = ((ci & 7) * 16) ^ ((row & 7) << 4);
        GLD16(A  + (size_t)(m0 + row) * K + k0 + (colb >> 1),
              As + (size_t)(r * 256 + w * 64) * 8);
        GLD16(Bm + (size_t)(n0 + row) * K + k0 + (colb >> 1),
              Bs + (size_t)(r * 256 + w * 64) * 8);
    }
}

template<bool FIRST>
DEV void kcompute(const u16* As, const u16* Bs, f32x4 (&acc)[4][4],
                  int wr, int wc, int lane)
{
    #pragma unroll
    for (int kk = 0; kk < 2; ++kk) {
        bf16x8 af[4], bf[4];
        const int cb = kk * 64 + ((lane >> 4) << 4);   // byte offset in row
        #pragma unroll
        for (int m = 0; m < 4; ++m) {
            const int row = wr * 64 + m * 16 + (lane & 15);
            af[m] = *(const bf16x8*)((const char*)As + row * 128 + (cb ^ ((row & 7) << 4)));
        }
        #pragma unroll
        for (int n = 0; n < 4; ++n) {
            const int row = wc * 64 + n * 16 + (lane & 15);
            bf[n] = *(const bf16x8*)((const char*)Bs + row * 128 + (cb ^ ((row & 7) << 4)));
        }
        #pragma unroll
        for (int m = 0; m < 4; ++m)
            #pragma unroll
            for (int n = 0; n < 4; ++n) {
                if (FIRST && kk == 0)
                    asm("v_mfma_f32_16x16x32_bf16 %0, %1, %2, 0"
                        : "=a"(acc[m][n]) : "v"(af[m]), "v"(bf[n]));
                else
                    asm("v_mfma_f32_16x16x32_bf16 %0, %1, %2, %0"
                        : "+a"(acc[m][n]) : "v"(af[m]), "v"(bf[n]));
            }
    }
}

// MODE 0: out bf16 = cos(c + bias[col])   (qa)  [__cosf: libm cosf spilled
//         the live-acc epilogue, round 8]
// MODE 1: out bf16 = relu(c + bias[col])  (h)
// MODE 2: out f32  = c + bias[col]        (ffn)
// MODE 3: out f32  = c                    (attn @ qa)
// MODE 4: out f32  = c * (1/sqrt(8))      (scores; f32 logits -- round 1)
template<int K, int MODE>
__global__ __launch_bounds__(256, 3)
void gemm_bt(const u16* __restrict__ A, const u16* __restrict__ Bm,
             const float* __restrict__ bias, void* __restrict__ out, int N,
             size_t sA, size_t sB, size_t sC)
{
    __shared__ u16 As[128 * 64];   // 16 KiB
    __shared__ u16 Bs[128 * 64];   // 16 KiB
    const int t = threadIdx.x;
    const int w = t >> 6, lane = t & 63;
    const int m0 = blockIdx.x * 128, n0 = blockIdx.y * 128;
    const int wr = w >> 1, wc = w & 1;     // 2 x 2 waves; wave tile 64x64
    A  += (size_t)blockIdx.z * sA;
    Bm += (size_t)blockIdx.z * sB;
    u16*   ob16 = (u16*)out   + (size_t)blockIdx.z * sC;
    float* of32 = (float*)out + (size_t)blockIdx.z * sC;
    f32x4 acc[4][4];               // written first by the C=0 MFMA form

    for (int k0 = 0; k0 < K; k0 += 64) {
        __syncthreads();                   // prev compute's LDS reads done
        kstage<K>(A, Bm, As, Bs, m0, n0, k0, w, t);
        __syncthreads();                   // staged tile ready (vmcnt drained)
        if (k0 == 0) kcompute<true >(As, Bs, acc, wr, wc, lane);
        else         kcompute<false>(As, Bs, acc, wr, wc, lane);
    }

    // hazard fence: MFMA(write acc) -> VALU/accvgpr_read in epilogue
    __builtin_amdgcn_sched_barrier(0);
    asm volatile("s_nop 7\n\ts_nop 7");
    __builtin_amdgcn_sched_barrier(0);

    // epilogue: C/D layout col = lane&15, row = (lane>>4)*4 + r
    #pragma unroll
    for (int m = 0; m < 4; ++m) {
        const int rowb = m0 + wr * 64 + m * 16 + ((lane >> 4) << 2);
        #pragma unroll
        for (int n = 0; n < 4; ++n) {
            const int col = n0 + wc * 64 + n * 16 + (lane & 15);
            float bv = 0.f;
            if (MODE == 0 || MODE == 1 || MODE == 2) bv = bias[col];
            #pragma unroll
            for (int r = 0; r < 4; ++r) {
                const float c = acc[m][n][r];
                const size_t idx = (size_t)(rowb + r) * N + col;
                if (MODE == 0)      ob16[idx] = f2b(__cosf(c + bv));
                else if (MODE == 1) ob16[idx] = f2b(fmaxf(c + bv, 0.f));
                else if (MODE == 2) of32[idx] = c + bv;
                else if (MODE == 3) of32[idx] = c;
                else                of32[idx] = c * 0.35355339059327373f;
            }
        }
    }
}

// ---------------------------------------------------------------------------
// 256x256 GEMM (r12-proven dbuf variant) -- used for ffn1 only: K=128 at
// 128^2 spreads 2 K-steps over 3072 blocks (~196 MB of L2-side re-reads);
// at 256^2 the grid is 768 blocks (full chip) and traffic halves.
// ---------------------------------------------------------------------------
template<int K>
DEV void kstage256(const u16* A, const u16* Bm, u16* As, u16* Bs,
                   int m0, int n0, int k0, int w, int t)
{
    #pragma unroll
    for (int r = 0; r < 4; ++r) {
        const int ci = r * 512 + t;
        const int row = ci >> 3;                       // 0..255
        const int colb = ((ci & 7) * 16) ^ ((row & 7) << 4);
        GLD16(A  + (size_t)(m0 + row) * K + k0 + (colb >> 1),
              As + (size_t)(r * 512 + w * 64) * 8);
        GLD16(Bm + (size_t)(n0 + row) * K + k0 + (colb >> 1),
              Bs + (size_t)(r * 512 + w * 64) * 8);
    }
}

template<bool FIRST>
DEV void kcompute256(const u16* As, const u16* Bs, f32x4 (&acc)[8][4],
                     int wr, int wc, int lane)
{
    #pragma unroll
    for (int kk = 0; kk < 2; ++kk) {
        bf16x8 af[8], bf[4];
        const int cb = kk * 64 + ((lane >> 4) << 4);
        #pragma unroll
        for (int m = 0; m < 8; ++m) {
            const int row = wr * 128 + m * 16 + (lane & 15);
            af[m] = *(const bf16x8*)((const char*)As + row * 128 + (cb ^ ((row & 7) << 4)));
        }
        #pragma unroll
        for (int n = 0; n < 4; ++n) {
            const int row = wc * 64 + n * 16 + (lane & 15);
            bf[n] = *(const bf16x8*)((const char*)Bs + row * 128 + (cb ^ ((row & 7) << 4)));
        }
        #pragma unroll
        for (int m = 0; m < 8; ++m)
            #pragma unroll
            for (int n = 0; n < 4; ++n) {
                if (FIRST && kk == 0)
                    asm("v_mfma_f32_16x16x32_bf16 %0, %1, %2, 0"
                        : "=a"(acc[m][n]) : "v"(af[m]), "v"(bf[n]));
                else
                    asm("v_mfma_f32_16x16x32_bf16 %0, %1, %2, %0"
                        : "+a"(acc[m][n]) : "v"(af[m]), "v"(bf[n]));
            }
    }
}

// MODE 1 only (h = relu(qf @ W1^T + b1))
template<int K, int MODE>
__global__ __launch_bounds__(512, 2)
void gemm_bt256(const u16* __restrict__ A, const u16* __restrict__ Bm,
                const float* __restrict__ bias, void* __restrict__ out, int N)
{
    __shared__ u16 lds[4 * 256 * 64];      // 128 KiB: [A0|B0][A1|B1]
    const int t = threadIdx.x;
    const int w = t >> 6, lane = t & 63;
    const int m0 = blockIdx.x * 256, n0 = blockIdx.y * 256;
    const int wr = w >> 2, wc = w & 3;     // 2 x 4 waves; wave tile 128x64
    u16* ob16 = (u16*)out;
    f32x4 acc[8][4];

    kstage256<K>(A, Bm, lds, lds + 16384, m0, n0, 0, w, t);
    __syncthreads();
    int cur = 0;
    for (int k0 = 0; k0 < K; k0 += 64) {
        const int nxt = cur ^ 32768;
        if (k0 + 64 < K)
            kstage256<K>(A, Bm, lds + nxt, lds + nxt + 16384, m0, n0, k0 + 64, w, t);
        if (k0 == 0) kcompute256<true >(lds + cur, lds + cur + 16384, acc, wr, wc, lane);
        else         kcompute256<false>(lds + cur, lds + cur + 16384, acc, wr, wc, lane);
        __syncthreads();
        cur = nxt;
    }

    __builtin_amdgcn_sched_barrier(0);
    asm volatile("s_nop 7\n\ts_nop 7");
    __builtin_amdgcn_sched_barrier(0);

    #pragma unroll
    for (int m = 0; m < 8; ++m) {
        const int rowb = m0 + wr * 128 + m * 16 + ((lane >> 4) << 2);
        #pragma unroll
        for (int n = 0; n < 4; ++n) {
            const int col = n0 + wc * 64 + n * 16 + (lane & 15);
            const float bv = bias[col];
            #pragma unroll
            for (int r = 0; r < 4; ++r) {
                const float c = acc[m][n][r];
                ob16[(size_t)(rowb + r) * N + col] = f2b(fmaxf(c + bv, 0.f));
            }
        }
    }
}

// ---------------------------------------------------------------------------
// Tiled bf16 transpose: in [B][S][E] -> out [B][E][S], 64x64 tiles.
// (Restored from rounds 2-11; fusing this into gemm0's epilogue made gemm0
// 4x less efficient than ffn2 -- scattered 4KB-stride ushort4 stores.)
// ---------------------------------------------------------------------------
__global__ __launch_bounds__(256)
void transpose_bf16(const u16* __restrict__ in, u16* __restrict__ outp)
{
    __shared__ u16 tile[64][72];
    const int b = blockIdx.z;
    const int s0 = blockIdx.x * 64, d0 = blockIdx.y * 64;
    const int t = threadIdx.x;
    const u16* src = in + ((size_t)b * S_ + s0) * E_ + d0;
    #pragma unroll
    for (int i = 0; i < 2; ++i) {
        const int r = (t >> 3) + i * 32;
        const int c = (t & 7) * 8;
        u16x8 v = *(const u16x8*)(src + (size_t)r * E_ + c);
        #pragma unroll
        for (int e = 0; e < 8; ++e) tile[r][c + e] = v[e];
    }
    __syncthreads();
    u16* dst = outp + ((size_t)b * E_ + d0) * S_ + s0;
    #pragma unroll
    for (int i = 0; i < 2; ++i) {
        const int r = (t >> 3) + i * 32;   // d-row within tile
        const int c = (t & 7) * 8;         // s-col
        u16x8 v;
        #pragma unroll
        for (int e = 0; e < 8; ++e) v[e] = tile[c + e][r];
        *(u16x8*)(dst + (size_t)r * S_ + c) = v;
    }
}

// ---------------------------------------------------------------------------
// Row softmax: read 2048 f32 logits, write 2048 bf16 probabilities.
// ---------------------------------------------------------------------------
__global__ __launch_bounds__(256)
void softmax_rows(const float* __restrict__ s, u16* __restrict__ pout)
{
    const int t = threadIdx.x;
    const float* row = s + (size_t)blockIdx.x * (size_t)S_;
    float f[8];
    {
        const float4 a = *(const float4*)(row + t * 8);
        const float4 b = *(const float4*)(row + t * 8 + 4);
        f[0] = a.x; f[1] = a.y; f[2] = a.z; f[3] = a.w;
        f[4] = b.x; f[5] = b.y; f[6] = b.z; f[7] = b.w;
    }
    float mx = f[0];
    #pragma unroll
    for (int e = 1; e < 8; ++e) mx = fmaxf(mx, f[e]);
    #pragma unroll
    for (int d = 1; d < 64; d <<= 1) mx = fmaxf(mx, __shfl_xor(mx, d));
    __shared__ float sh[8];
    if ((t & 63) == 0) sh[t >> 6] = mx;
    __syncthreads();
    mx = fmaxf(fmaxf(sh[0], sh[1]), fmaxf(sh[2], sh[3]));
    float sum = 0.f;
    #pragma unroll
    for (int e = 0; e < 8; ++e) { f[e] = __expf(f[e] - mx); sum += f[e]; }
    #pragma unroll
    for (int d = 1; d < 64; d <<= 1) sum += __shfl_xor(sum, d);
    if ((t & 63) == 0) sh[4 + (t >> 6)] = sum;
    __syncthreads();
    sum = sh[4] + sh[5] + sh[6] + sh[7];
    const float inv = 1.f / sum;
    u16x8 v;
    #pragma unroll
    for (int e = 0; e < 8; ++e) v[e] = f2b(f[e] * inv);
    *(u16x8*)(pout + (size_t)blockIdx.x * (size_t)S_ + t * 8) = v;
}

// ---------------------------------------------------------------------------
// Fused residual + LayerNorm (+ optional qf = cos(y[:128] + theta) epilogue).
// ---------------------------------------------------------------------------
__global__ __launch_bounds__(256)
void ln_fuse(const float* __restrict__ a, const float* __restrict__ res,
             const float* __restrict__ g, const float* __restrict__ bb,
             const float* __restrict__ theta, float* __restrict__ out,
             u16* __restrict__ qf)
{
    const int row = blockIdx.x, t = threadIdx.x;
    const float* ar = a + (size_t)row * E_;
    const float* rr = res + (size_t)row * E_;
    float v0 = ar[t] + rr[t];
    float v1 = ar[t + 256] + rr[t + 256];
    float v2 = ar[t + 512] + rr[t + 512];
    float s1 = v0 + v1 + v2;
    float s2 = v0 * v0 + v1 * v1 + v2 * v2;
    #pragma unroll
    for (int d = 1; d < 64; d <<= 1) { s1 += __shfl_xor(s1, d); s2 += __shfl_xor(s2, d); }
    __shared__ float sh[8];
    if ((t & 63) == 0) { sh[t >> 6] = s1; sh[4 + (t >> 6)] = s2; }
    __syncthreads();
    s1 = sh[0] + sh[1] + sh[2] + sh[3];
    s2 = sh[4] + sh[5] + sh[6] + sh[7];
    const float mean = s1 * (1.f / 768.f);
    const float var = s2 * (1.f / 768.f) - mean * mean;
    const float rs = rsqrtf(var + 1e-5f);
    float* orow = out + (size_t)row * E_;
    const float y0 = (v0 - mean) * rs * g[t] + bb[t];
    const float y1 = (v1 - mean) * rs * g[t + 256] + bb[t + 256];
    const float y2 = (v2 - mean) * rs * g[t + 512] + bb[t + 512];
    orow[t] = y0; orow[t + 256] = y1; orow[t + 512] = y2;
    if (qf != nullptr && t < NQ_)
        qf[(size_t)row * NQ_ + t] = f2b(cosf(y0 + theta[t]));
}

// ---------------------------------------------------------------------------
// Workspace arena plan (216 MiB arena + 5.25 MiB fixed tail).
// Timeline:  t0 cvt | t1 gemm0 | t2 transpose | t3 scores | t4 softmax
//            t5 PV  | t6 ln1   | t7 ffn1      | t8 ffn2   | t9 ln2
// buffer   offset(MiB) size  live
//  x_b        0       24    t0-t1
//  Wp_b      24       1.13  t0-t1
//  qa       128       24    t1-t3
//  qaT      192       24    t2-t5
//  scores     0      128    t3-t4
//  probs    128       64    t4-t5
//  ao         0       48    t5-t6,t8-t9
//  x1       144       48    t6-t9
//  qf       192        4    t6-t7
//  h         48       96    t7-t8
// ---------------------------------------------------------------------------
extern "C" void kernel_launch(void* const* d_in, const int* in_sizes, int n_in,
                              void* d_out, int out_size, void* d_ws, size_t ws_size,
                              hipStream_t stream)
{
    (void)in_sizes; (void)n_in; (void)out_size;
    const float* x    = (const float*)d_in[0];
    const float* Wp   = (const float*)d_in[1];
    const float* trx  = (const float*)d_in[2];
    const float* try_ = (const float*)d_in[3];
    const float* W1   = (const float*)d_in[4];
    const float* b1   = (const float*)d_in[5];
    const float* W2   = (const float*)d_in[6];
    const float* b2   = (const float*)d_in[7];
    const float* g1   = (const float*)d_in[8];
    const float* bb1  = (const float*)d_in[9];
    const float* g2   = (const float*)d_in[10];
    const float* bb2  = (const float*)d_in[11];
    float* out = (float*)d_out;

    const size_t MiB = (size_t)1 << 20;
    char* arena = (char*)d_ws;
    u16*   x_b    = (u16*)  (arena + 0);
    u16*   Wp_b   = (u16*)  (arena + 24 * MiB);
    u16*   qa     = (u16*)  (arena + 128 * MiB);
    u16*   qaT    = (u16*)  (arena + 192 * MiB);
    float* scores = (float*)(arena + 0);
    u16*   probs  = (u16*)  (arena + 128 * MiB);
    float* ao     = (float*)(arena + 0);
    float* x1     = (float*)(arena + 144 * MiB);
    u16*   qf     = (u16*)  (arena + 192 * MiB);
    u16*   h      = (u16*)  (arena + 48 * MiB);
    u16*   W1_b   = (u16*)  (arena + 216 * MiB);
    u16*   W2_b   = (u16*)  (arena + 216 * MiB + (size_t)FF_ * NQ_ * 2);
    const size_t need = 216 * MiB + (size_t)FF_ * NQ_ * 2 + (size_t)E_ * FF_ * 2;
    if (need > ws_size) {
        fprintf(stderr, "kernel_launch: ws too small: need=%zu have=%zu\n", need, ws_size);
        return;
    }

    cvt_bf16<<<512, 256, 0, stream>>>(x,  x_b,  BS_ * E_);
    cvt_bf16<<<64,  256, 0, stream>>>(Wp, Wp_b, E_ * E_);
    cvt_bf16<<<64,  256, 0, stream>>>(W1, W1_b, FF_ * NQ_);
    cvt_bf16<<<64,  256, 0, stream>>>(W2, W2_b, E_ * FF_);

    // qa = cos(x @ Wp^T + theta_rx)
    gemm_bt<E_, 0><<<dim3(BS_ / 128, E_ / 128), 256, 0, stream>>>(
        x_b, Wp_b, trx, qa, E_, 0, 0, 0);
    // qaT[b][d][s] = qa[b][s][d]  (coalesced LDS-tiled transpose)
    transpose_bf16<<<dim3(S_ / 64, E_ / 64, B_), 256, 0, stream>>>(qa, qaT);
    // scores = (qa @ qa^T) / sqrt(8), f32, per batch
    gemm_bt<E_, 4><<<dim3(S_ / 128, S_ / 128, B_), 256, 0, stream>>>(
        qa, qa, nullptr, scores, S_,
        (size_t)S_ * E_, (size_t)S_ * E_, (size_t)S_ * S_);
    // probs = softmax(scores) in bf16
    softmax_rows<<<BS_, 256, 0, stream>>>(scores, probs);
    // ao = probs @ qa  (= probs [S,S] * qaT [E,S]^T), f32, per batch
    gemm_bt<S_, 3><<<dim3(S_ / 128, E_ / 128, B_), 256, 0, stream>>>(
        probs, qaT, nullptr, ao, E_,
        (size_t)S_ * S_, (size_t)E_ * S_, (size_t)S_ * E_);

    ln_fuse<<<BS_, 256, 0, stream>>>(ao, x, g1, bb1, try_, x1, qf);
    // ffn1 at 256^2 (full-chip 768-block grid; halves L2-side re-reads)
    gemm_bt256<NQ_, 1><<<dim3(BS_ / 256, FF_ / 256), 512, 0, stream>>>(
        qf, W1_b, b1, h, FF_);
    gemm_bt<FF_, 2><<<dim3(BS_ / 128, E_ / 128), 256, 0, stream>>>(
        h, W2_b, b2, ao, E_, 0, 0, 0);
    ln_fuse<<<BS_, 256, 0, stream>>>(ao, x1, g2, bb2, nullptr, out, nullptr);
}

// Round 17
// 404.717 us; speedup vs baseline: 1.0799x; 1.0129x over previous
//
#include <hip/hip_runtime.h>
#include <hip/hip_bf16.h>
#include <cstdio>
#include <cstdint>

typedef __bf16 bf16x8 __attribute__((ext_vector_type(8)));
typedef unsigned short u16;
typedef u16 u16x8 __attribute__((ext_vector_type(8)));
typedef float f32x4 __attribute__((ext_vector_type(4)));

#define DEV __device__ __forceinline__

static constexpr int B_ = 8, S_ = 2048, E_ = 768, NQ_ = 128, FF_ = 3072;
static constexpr int BS_ = B_ * S_;

DEV u16 f2b(float f) {
    unsigned u = __builtin_bit_cast(unsigned, f);
    unsigned r = (u + 0x7fffu + ((u >> 16) & 1u)) >> 16;
    return (u16)r;
}

#define GLD16(gp, lp) __builtin_amdgcn_global_load_lds( \
    (const __attribute__((address_space(1))) void*)(gp), \
    (__attribute__((address_space(3))) void*)(lp), 16, 0, 0)

// ---------------------------------------------------------------------------
// f32 -> bf16 convert (vectorized float4 -> ushort4)
// ---------------------------------------------------------------------------
__global__ void cvt_bf16(const float* __restrict__ in, u16* __restrict__ out, int n)
{
    const int stride = gridDim.x * blockDim.x * 4;
    for (int i = (blockIdx.x * blockDim.x + threadIdx.x) * 4; i < n; i += stride) {
        const float4 f = *(const float4*)(in + i);
        ushort4 u;
        u.x = f2b(f.x); u.y = f2b(f.y); u.z = f2b(f.z); u.w = f2b(f.w);
        *(ushort4*)(out + i) = u;
    }
}

// ---------------------------------------------------------------------------
// 128x128 GEMM, BK=64, 4 waves (2x2 of 64x64), 256 threads, single-buffer
// LDS (32 KiB) + 2 barriers/K-step, 3 blocks/CU -- the session champion
// operating point (round 13, 406 us).
//
// Session evidence locking this shape:
//  - asm-AGPR accumulator (r2-8): compiler never promotes the acc array ->
//    scratch spill (0.9-1.25 GB writes/dispatch).  "a" constraints +
//    (1) first MFMA src-C = inline 0 ("=a"), (2) s_nop fence before the
//    epilogue's accvgpr reads.  MFMA->MFMA chains are HW-interlocked.
//  - __cosf in MODE 0 (r10): libm cosf's reg footprint spilled the
//    live-acc epilogue (614 MB scratch writes).
//  - 128^2 single-buf @3 blocks/CU (r13, 406us) beats 256^2 dbuf (r12,
//    411), 128^2 dbuf @2 blocks/CU (r15, 437), counted-vmcnt BK=32 (r11,
//    438), XCD swizzle (r14, 414: L3 thrash, FETCH 93->301 MB), unfused
//    transpose + ffn1@256^2 (r16, 410).
//  - BK=64 row-swizzle ((row&7)<<4 byte-XOR): 0 bank conflicts.
//  - Deep-K GEMMs at ~800 TF = the m97-structure-family ceiling; escaping
//    it needs the full 8-phase counted-vmcnt schedule (not safely
//    reconstructible here).
// ---------------------------------------------------------------------------
template<int K>
DEV void kstage(const u16* A, const u16* Bm, u16* As, u16* Bs,
                int m0, int n0, int k0, int w, int t)
{
    #pragma unroll
    for (int r = 0; r < 4; ++r) {
        const int ci = r * 256 + t;
        const int row = ci >> 3;                       // 0..127
        const int colb = ((ci & 7) * 16) ^ ((row & 7) << 4);
        GLD16(A  + (size_t)(m0 + row) * K + k0 + (colb >> 1),
              As + (size_t)(r * 256 + w * 64) * 8);
        GLD16(Bm + (size_t)(n0 + row) * K + k0 + (colb >> 1),
              Bs + (size_t)(r * 256 + w * 64) * 8);
    }
}

template<bool FIRST>
DEV void kcompute(const u16* As, const u16* Bs, f32x4 (&acc)[4][4],
                  int wr, int wc, int lane)
{
    #pragma unroll
    for (int kk = 0; kk < 2; ++kk) {
        bf16x8 af[4], bf[4];
        const int cb = kk * 64 + ((lane >> 4) << 4);   // byte offset in row
        #pragma unroll
        for (int m = 0; m < 4; ++m) {
            const int row = wr * 64 + m * 16 + (lane & 15);
            af[m] = *(const bf16x8*)((const char*)As + row * 128 + (cb ^ ((row & 7) << 4)));
        }
        #pragma unroll
        for (int n = 0; n < 4; ++n) {
            const int row = wc * 64 + n * 16 + (lane & 15);
            bf[n] = *(const bf16x8*)((const char*)Bs + row * 128 + (cb ^ ((row & 7) << 4)));
        }
        #pragma unroll
        for (int m = 0; m < 4; ++m)
            #pragma unroll
            for (int n = 0; n < 4; ++n) {
                if (FIRST && kk == 0)
                    asm("v_mfma_f32_16x16x32_bf16 %0, %1, %2, 0"
                        : "=a"(acc[m][n]) : "v"(af[m]), "v"(bf[n]));
                else
                    asm("v_mfma_f32_16x16x32_bf16 %0, %1, %2, %0"
                        : "+a"(acc[m][n]) : "v"(af[m]), "v"(bf[n]));
            }
    }
}

// MODE 0: out bf16 = cos(c + bias[col]); aux = qaT       (qa)
// MODE 1: out bf16 = relu(c + bias[col])                 (h)
// MODE 2: out f32  = c + bias[col]                       (ffn)
// MODE 3: out f32  = c                                   (attn @ qa)
// MODE 4: out f32  = c * (1/sqrt(8))                     (scores; f32 logits)
template<int K, int MODE>
__global__ __launch_bounds__(256, 3)
void gemm_bt(const u16* __restrict__ A, const u16* __restrict__ Bm,
             const float* __restrict__ bias, void* __restrict__ out, int N,
             size_t sA, size_t sB, size_t sC, u16* __restrict__ aux)
{
    __shared__ u16 As[128 * 64];   // 16 KiB
    __shared__ u16 Bs[128 * 64];   // 16 KiB
    const int t = threadIdx.x;
    const int w = t >> 6, lane = t & 63;
    const int m0 = blockIdx.x * 128, n0 = blockIdx.y * 128;
    const int wr = w >> 1, wc = w & 1;     // 2 x 2 waves; wave tile 64x64
    A  += (size_t)blockIdx.z * sA;
    Bm += (size_t)blockIdx.z * sB;
    u16*   ob16 = (u16*)out   + (size_t)blockIdx.z * sC;
    float* of32 = (float*)out + (size_t)blockIdx.z * sC;
    f32x4 acc[4][4];               // written first by the C=0 MFMA form

    for (int k0 = 0; k0 < K; k0 += 64) {
        __syncthreads();                   // prev compute's LDS reads done
        kstage<K>(A, Bm, As, Bs, m0, n0, k0, w, t);
        __syncthreads();                   // staged tile ready (vmcnt drained)
        if (k0 == 0) kcompute<true >(As, Bs, acc, wr, wc, lane);
        else         kcompute<false>(As, Bs, acc, wr, wc, lane);
    }

    // hazard fence: MFMA(write acc) -> VALU/accvgpr_read in epilogue
    __builtin_amdgcn_sched_barrier(0);
    asm volatile("s_nop 7\n\ts_nop 7");
    __builtin_amdgcn_sched_barrier(0);

    // epilogue: C/D layout col = lane&15, row = (lane>>4)*4 + r
    #pragma unroll
    for (int m = 0; m < 4; ++m) {
        const int rowb = m0 + wr * 64 + m * 16 + ((lane >> 4) << 2);
        #pragma unroll
        for (int n = 0; n < 4; ++n) {
            const int col = n0 + wc * 64 + n * 16 + (lane & 15);
            float bv = 0.f;
            if (MODE == 0 || MODE == 1 || MODE == 2) bv = bias[col];
            ushort4 tq;
            #pragma unroll
            for (int r = 0; r < 4; ++r) {
                const float c = acc[m][n][r];
                const size_t idx = (size_t)(rowb + r) * N + col;
                if (MODE == 0) {
                    const u16 v = f2b(__cosf(c + bv));
                    ob16[idx] = v;
                    ((u16*)&tq)[r] = v;
                }
                else if (MODE == 1) ob16[idx] = f2b(fmaxf(c + bv, 0.f));
                else if (MODE == 2) of32[idx] = c + bv;
                else if (MODE == 3) of32[idx] = c;
                else                of32[idx] = c * 0.35355339059327373f;
            }
            if (MODE == 0) {
                // qaT[b][col][srow..srow+3] (4-row quad is 128-tile-internal,
                // batches 2048-aligned -> never straddles a batch)
                const int b = rowb >> 11, srow = rowb & 2047;
                *(ushort4*)(aux + ((size_t)b * E_ + col) * S_ + srow) = tq;
            }
        }
    }
}

// ---------------------------------------------------------------------------
// Row softmax: read 2048 f32 logits, write 2048 bf16 probabilities.
// One block per row, 256 threads x 8 elements.
// ---------------------------------------------------------------------------
__global__ __launch_bounds__(256)
void softmax_rows(const float* __restrict__ s, u16* __restrict__ pout)
{
    const int t = threadIdx.x;
    const float* row = s + (size_t)blockIdx.x * (size_t)S_;
    float f[8];
    {
        const float4 a = *(const float4*)(row + t * 8);
        const float4 b = *(const float4*)(row + t * 8 + 4);
        f[0] = a.x; f[1] = a.y; f[2] = a.z; f[3] = a.w;
        f[4] = b.x; f[5] = b.y; f[6] = b.z; f[7] = b.w;
    }
    float mx = f[0];
    #pragma unroll
    for (int e = 1; e < 8; ++e) mx = fmaxf(mx, f[e]);
    #pragma unroll
    for (int d = 1; d < 64; d <<= 1) mx = fmaxf(mx, __shfl_xor(mx, d));
    __shared__ float sh[8];
    if ((t & 63) == 0) sh[t >> 6] = mx;
    __syncthreads();
    mx = fmaxf(fmaxf(sh[0], sh[1]), fmaxf(sh[2], sh[3]));
    float sum = 0.f;
    #pragma unroll
    for (int e = 0; e < 8; ++e) { f[e] = __expf(f[e] - mx); sum += f[e]; }
    #pragma unroll
    for (int d = 1; d < 64; d <<= 1) sum += __shfl_xor(sum, d);
    if ((t & 63) == 0) sh[4 + (t >> 6)] = sum;
    __syncthreads();
    sum = sh[4] + sh[5] + sh[6] + sh[7];
    const float inv = 1.f / sum;
    u16x8 v;
    #pragma unroll
    for (int e = 0; e < 8; ++e) v[e] = f2b(f[e] * inv);
    *(u16x8*)(pout + (size_t)blockIdx.x * (size_t)S_ + t * 8) = v;
}

// ---------------------------------------------------------------------------
// Fused residual + LayerNorm (+ optional qf = cos(y[:128] + theta) epilogue).
// One block per row (768 cols, 256 threads x 3).
// ---------------------------------------------------------------------------
__global__ __launch_bounds__(256)
void ln_fuse(const float* __restrict__ a, const float* __restrict__ res,
             const float* __restrict__ g, const float* __restrict__ bb,
             const float* __restrict__ theta, float* __restrict__ out,
             u16* __restrict__ qf)
{
    const int row = blockIdx.x, t = threadIdx.x;
    const float* ar = a + (size_t)row * E_;
    const float* rr = res + (size_t)row * E_;
    float v0 = ar[t] + rr[t];
    float v1 = ar[t + 256] + rr[t + 256];
    float v2 = ar[t + 512] + rr[t + 512];
    float s1 = v0 + v1 + v2;
    float s2 = v0 * v0 + v1 * v1 + v2 * v2;
    #pragma unroll
    for (int d = 1; d < 64; d <<= 1) { s1 += __shfl_xor(s1, d); s2 += __shfl_xor(s2, d); }
    __shared__ float sh[8];
    if ((t & 63) == 0) { sh[t >> 6] = s1; sh[4 + (t >> 6)] = s2; }
    __syncthreads();
    s1 = sh[0] + sh[1] + sh[2] + sh[3];
    s2 = sh[4] + sh[5] + sh[6] + sh[7];
    const float mean = s1 * (1.f / 768.f);
    const float var = s2 * (1.f / 768.f) - mean * mean;
    const float rs = rsqrtf(var + 1e-5f);
    float* orow = out + (size_t)row * E_;
    const float y0 = (v0 - mean) * rs * g[t] + bb[t];
    const float y1 = (v1 - mean) * rs * g[t + 256] + bb[t + 256];
    const float y2 = (v2 - mean) * rs * g[t + 512] + bb[t + 512];
    orow[t] = y0; orow[t + 256] = y1; orow[t + 512] = y2;
    if (qf != nullptr && t < NQ_)
        qf[(size_t)row * NQ_ + t] = f2b(cosf(y0 + theta[t]));
}

// ---------------------------------------------------------------------------
// Workspace arena plan (216 MiB arena + 5.25 MiB fixed tail).
// Timeline:  t0 cvt | t1 gemm0 (writes qa + qaT) | t3 scores | t4 softmax
//            t5 PV  | t6 ln1   | t7 ffn1         | t8 ffn2   | t9 ln2
// buffer   offset(MiB) size  live
//  x_b        0       24    t0-t1
//  Wp_b      24       1.13  t0-t1
//  qa       128       24    t1-t3
//  qaT      192       24    t1-t5
//  scores     0      128    t3-t4
//  probs    128       64    t4-t5
//  ao         0       48    t5-t6,t8-t9
//  x1       144       48    t6-t9
//  qf       192        4    t6-t7
//  h         48       96    t7-t8
// ---------------------------------------------------------------------------
extern "C" void kernel_launch(void* const* d_in, const int* in_sizes, int n_in,
                              void* d_out, int out_size, void* d_ws, size_t ws_size,
                              hipStream_t stream)
{
    (void)in_sizes; (void)n_in; (void)out_size;
    const float* x    = (const float*)d_in[0];
    const float* Wp   = (const float*)d_in[1];
    const float* trx  = (const float*)d_in[2];
    const float* try_ = (const float*)d_in[3];
    const float* W1   = (const float*)d_in[4];
    const float* b1   = (const float*)d_in[5];
    const float* W2   = (const float*)d_in[6];
    const float* b2   = (const float*)d_in[7];
    const float* g1   = (const float*)d_in[8];
    const float* bb1  = (const float*)d_in[9];
    const float* g2   = (const float*)d_in[10];
    const float* bb2  = (const float*)d_in[11];
    float* out = (float*)d_out;

    const size_t MiB = (size_t)1 << 20;
    char* arena = (char*)d_ws;
    u16*   x_b    = (u16*)  (arena + 0);
    u16*   Wp_b   = (u16*)  (arena + 24 * MiB);
    u16*   qa     = (u16*)  (arena + 128 * MiB);
    u16*   qaT    = (u16*)  (arena + 192 * MiB);
    float* scores = (float*)(arena + 0);
    u16*   probs  = (u16*)  (arena + 128 * MiB);
    float* ao     = (float*)(arena + 0);
    float* x1     = (float*)(arena + 144 * MiB);
    u16*   qf     = (u16*)  (arena + 192 * MiB);
    u16*   h      = (u16*)  (arena + 48 * MiB);
    u16*   W1_b   = (u16*)  (arena + 216 * MiB);
    u16*   W2_b   = (u16*)  (arena + 216 * MiB + (size_t)FF_ * NQ_ * 2);
    const size_t need = 216 * MiB + (size_t)FF_ * NQ_ * 2 + (size_t)E_ * FF_ * 2;
    if (need > ws_size) {
        fprintf(stderr, "kernel_launch: ws too small: need=%zu have=%zu\n", need, ws_size);
        return;
    }

    cvt_bf16<<<512, 256, 0, stream>>>(x,  x_b,  BS_ * E_);
    cvt_bf16<<<64,  256, 0, stream>>>(Wp, Wp_b, E_ * E_);
    cvt_bf16<<<64,  256, 0, stream>>>(W1, W1_b, FF_ * NQ_);
    cvt_bf16<<<64,  256, 0, stream>>>(W2, W2_b, E_ * FF_);

    // qa = cos(x @ Wp^T + theta_rx); epilogue also writes qaT[b][d][s]
    gemm_bt<E_, 0><<<dim3(BS_ / 128, E_ / 128), 256, 0, stream>>>(
        x_b, Wp_b, trx, qa, E_, 0, 0, 0, qaT);
    // scores = (qa @ qa^T) / sqrt(8), f32, per batch
    gemm_bt<E_, 4><<<dim3(S_ / 128, S_ / 128, B_), 256, 0, stream>>>(
        qa, qa, nullptr, scores, S_,
        (size_t)S_ * E_, (size_t)S_ * E_, (size_t)S_ * S_, nullptr);
    // probs = softmax(scores) in bf16
    softmax_rows<<<BS_, 256, 0, stream>>>(scores, probs);
    // ao = probs @ qa  (= probs [S,S] * qaT [E,S]^T), f32, per batch
    gemm_bt<S_, 3><<<dim3(S_ / 128, E_ / 128, B_), 256, 0, stream>>>(
        probs, qaT, nullptr, ao, E_,
        (size_t)S_ * S_, (size_t)E_ * S_, (size_t)S_ * E_, nullptr);

    ln_fuse<<<BS_, 256, 0, stream>>>(ao, x, g1, bb1, try_, x1, qf);
    gemm_bt<NQ_, 1><<<dim3(BS_ / 128, FF_ / 128), 256, 0, stream>>>(
        qf, W1_b, b1, h, FF_, 0, 0, 0, nullptr);
    gemm_bt<FF_, 2><<<dim3(BS_ / 128, E_ / 128), 256, 0, stream>>>(
        h, W2_b, b2, ao, E_, 0, 0, 0, nullptr);
    ln_fuse<<<BS_, 256, 0, stream>>>(ao, x1, g2, bb2, nullptr, out, nullptr);
}